// Round 10
// baseline (171.062 us; speedup 1.0000x reference)
//
#include <hip/hip_runtime.h>
#include <math.h>

#define NB 2
#define NS 8192
#define NE 128
#define NROWS (NB * NS)

typedef __attribute__((ext_vector_type(8))) short s8v;    // 8 bf16 MFMA frag
typedef __attribute__((ext_vector_type(16))) float fx16;  // 32x32 accumulator
typedef __attribute__((ext_vector_type(2))) unsigned int u2v;
typedef __attribute__((address_space(1))) const unsigned char as1c;
typedef __attribute__((address_space(3))) unsigned char as3t;

static __device__ __forceinline__ unsigned int pkbf(float a, float b) {
    unsigned int ua = __float_as_uint(a), ub = __float_as_uint(b);
    ua += 0x7FFFu + ((ua >> 16) & 1u);
    ub += 0x7FFFu + ((ub >> 16) & 1u);
    return (ua >> 16) | (ub & 0xFFFF0000u);
}

// HW packed f32->bf16 (RNE), 1 instr for 2 elements (no builtin on gfx950)
static __device__ __forceinline__ unsigned int cvtpk(float a, float b) {
    unsigned int r;
    asm("v_cvt_pk_bf16_f32 %0, %1, %2" : "=v"(r) : "v"(a), "v"(b));
    return r;
}

// hi/lo split of 8 consecutive floats -> two uint4 of 8 bf16 each
static __device__ __forceinline__ void split8(const float* p, uint4& H, uint4& L) {
    float4 a = *(const float4*)p;
    float4 b = *(const float4*)(p + 4);
    unsigned int h0 = cvtpk(a.x, a.y), h1 = cvtpk(a.z, a.w);
    unsigned int h2 = cvtpk(b.x, b.y), h3 = cvtpk(b.z, b.w);
    H = make_uint4(h0, h1, h2, h3);
    float l0 = a.x - __uint_as_float(h0 << 16);
    float l1 = a.y - __uint_as_float(h0 & 0xFFFF0000u);
    float l2 = a.z - __uint_as_float(h1 << 16);
    float l3 = a.w - __uint_as_float(h1 & 0xFFFF0000u);
    float l4 = b.x - __uint_as_float(h2 << 16);
    float l5 = b.y - __uint_as_float(h2 & 0xFFFF0000u);
    float l6 = b.z - __uint_as_float(h3 << 16);
    float l7 = b.w - __uint_as_float(h3 & 0xFFFF0000u);
    L = make_uint4(cvtpk(l0, l1), cvtpk(l2, l3), cvtpk(l4, l5), cvtpk(l6, l7));
}

// ---------------------------------------------------------------------------
// One-shot hi/lo split of x (blocks 0..1023) and W (blocks 1024..1047).
// ---------------------------------------------------------------------------
__global__ __launch_bounds__(256, 4)
void split_kernel(const float* __restrict__ x,
                  const float* __restrict__ Wq, const float* __restrict__ Wk,
                  const float* __restrict__ Wv,
                  unsigned short* __restrict__ xh, unsigned short* __restrict__ xl,
                  unsigned short* __restrict__ WhS, unsigned short* __restrict__ WlS)
{
    const int bid = blockIdx.x;
    if (bid < 1024) {
        const int i = (bid * 256 + threadIdx.x) * 8;
        uint4 H, L;
        split8(&x[i], H, L);
        *(uint4*)&xh[i] = H;
        *(uint4*)&xl[i] = L;
    } else {
        const int tid = (bid - 1024) * 256 + threadIdx.x;  // 6144 granule tasks
        const int mat = tid >> 11;
        const int rem = tid & 2047;
        const int r = rem >> 4, g = rem & 15;
        const float* W = (mat == 0) ? Wq : (mat == 1) ? Wk : Wv;
        uint4 H, L;
        split8(&W[r * 128 + g * 8], H, L);
        const int gs = g ^ (r & 7);
        *(uint4*)&WhS[mat * 16384 + r * 128 + gs * 8] = H;
        *(uint4*)&WlS[mat * 16384 + r * 128 + gs * 8] = L;
    }
}

// ---------------------------------------------------------------------------
// QKV projection v3 (unchanged from r7): transaction-coalesced both sides.
// ---------------------------------------------------------------------------
__global__ __launch_bounds__(256, 2)
void qkv_kernel(const unsigned short* __restrict__ xh,
                const unsigned short* __restrict__ xl,
                const unsigned short* __restrict__ WhS,
                const unsigned short* __restrict__ WlS,
                const float* __restrict__ bq, const float* __restrict__ bk,
                const float* __restrict__ bv,
                unsigned short* __restrict__ qkv)
{
    __shared__ unsigned short xhL[64 * 128];   // 16KB
    __shared__ unsigned short xlL[64 * 128];   // 16KB
    __shared__ unsigned short WhL[64 * 128];   // 16KB
    __shared__ unsigned short WlL[64 * 128];   // 16KB

    const int t    = threadIdx.x;
    const int rblk = blockIdx.x * 64;
    const int mat  = blockIdx.y;
    const int o0   = blockIdx.z * 64;

    const float* bias = (mat == 0) ? bq : (mat == 1) ? bk : bv;
    unsigned short* out = qkv + (size_t)mat * NROWS * NE;
    const float osc = (mat == 0) ? 0.1275174460620886f : 1.0f;  // log2(e)/sqrt(128)

    const int w = t >> 6, lane = t & 63, lq = lane & 31, h = lane >> 5;

    // ---- stage: wave0 -> xh tile, wave1 -> xl tile, wave2/3 -> Wh/Wl ----
    if (w < 2) {
        const unsigned short* src = (w == 0) ? xh : xl;
        unsigned short* dst = (w == 0) ? xhL : xlL;
        const int rb4 = lane >> 4;        // 0..3
        const int cg  = lane & 15;        // granule slot
        #pragma unroll
        for (int i = 0; i < 16; ++i) {
            const int row = 4 * i + rb4;              // 0..63 local
            const int c   = cg ^ (row & 7);           // pre-swizzled source granule
            __builtin_amdgcn_global_load_lds(
                (as1c*)(src + (size_t)(rblk + row) * NE + c * 8),
                (as3t*)(dst + i * 512 + lane * 8), 16, 0, 0);
        }
    } else {
        const unsigned short* src = ((w == 2) ? WhS : WlS) + mat * 16384 + o0 * 128;
        unsigned short* dst = (w == 2) ? WhL : WlL;
        #pragma unroll
        for (int i = 0; i < 16; ++i) {
            __builtin_amdgcn_global_load_lds(
                (as1c*)(src + i * 512 + lane * 8),
                (as3t*)(dst + i * 512 + lane * 8), 16, 0, 0);
        }
    }
    __syncthreads();

    // ---- per-wave quadrant: rows rloc..rloc+31, out cols ot*32..+31 ----
    const int rloc = (w & 1) * 32;
    const int ot   = w >> 1;

    s8v xhf[8], xlf[8], whf[8], wlf[8];
    #pragma unroll
    for (int s = 0; s < 8; ++s) {
        const int cx = ((s * 2 + h) ^ (lq & 7)) * 8;
        xhf[s] = *(const s8v*)&xhL[(rloc + lq) * 128 + cx];
        xlf[s] = *(const s8v*)&xlL[(rloc + lq) * 128 + cx];
        whf[s] = *(const s8v*)&WhL[(ot * 32 + lq) * 128 + cx];
        wlf[s] = *(const s8v*)&WlL[(ot * 32 + lq) * 128 + cx];
    }

    fx16 acc;
    #pragma unroll
    for (int i = 0; i < 16; ++i) acc[i] = 0.f;

    #pragma unroll
    for (int s = 0; s < 8; ++s) {
        if (mat != 2) {
            acc = __builtin_amdgcn_mfma_f32_32x32x16_bf16(whf[s], xhf[s], acc, 0, 0, 0);
            acc = __builtin_amdgcn_mfma_f32_32x32x16_bf16(whf[s], xlf[s], acc, 0, 0, 0);
            acc = __builtin_amdgcn_mfma_f32_32x32x16_bf16(wlf[s], xhf[s], acc, 0, 0, 0);
        } else {
            acc = __builtin_amdgcn_mfma_f32_32x32x16_bf16(xhf[s], whf[s], acc, 0, 0, 0);
            acc = __builtin_amdgcn_mfma_f32_32x32x16_bf16(xlf[s], whf[s], acc, 0, 0, 0);
            acc = __builtin_amdgcn_mfma_f32_32x32x16_bf16(xhf[s], wlf[s], acc, 0, 0, 0);
        }
    }

    // ---- transpose epilogue through LDS (reuse staging space) ----
    __syncthreads();   // all frag reads done before overwrite
    unsigned short* TB = xhL;   // needs <= 64*72*2 = 9.2KB

    if (mat != 2) {
        #pragma unroll
        for (int g = 0; g < 4; ++g) {
            const int ob = o0 + ot * 32 + 4 * h + 8 * g;
            float4 bb = *(const float4*)&bias[ob];
            float v0 = (acc[4 * g + 0] + bb.x) * osc;
            float v1 = (acc[4 * g + 1] + bb.y) * osc;
            float v2 = (acc[4 * g + 2] + bb.z) * osc;
            float v3 = (acc[4 * g + 3] + bb.w) * osc;
            *(uint2*)&TB[(rloc + lq) * 72 + ot * 32 + 4 * h + 8 * g] =
                make_uint2(pkbf(v0, v1), pkbf(v2, v3));
        }
        __syncthreads();
        #pragma unroll
        for (int it = 0; it < 2; ++it) {
            const int r2 = it * 32 + (t >> 3);
            const int c2 = (t & 7) * 8;
            uint4 vv = *(const uint4*)&TB[r2 * 72 + c2];
            *(uint4*)&out[(size_t)(rblk + r2) * NE + o0 + c2] = vv;
        }
    } else {
        const float bv_ = bias[o0 + ot * 32 + lq];
        #pragma unroll
        for (int g = 0; g < 4; ++g) {
            float v0 = acc[4 * g + 0] + bv_;
            float v1 = acc[4 * g + 1] + bv_;
            float v2 = acc[4 * g + 2] + bv_;
            float v3 = acc[4 * g + 3] + bv_;
            *(uint2*)&TB[(ot * 32 + lq) * 72 + rloc + 4 * h + 8 * g] =
                make_uint2(pkbf(v0, v1), pkbf(v2, v3));
        }
        __syncthreads();
        const int bb_ = rblk >> 13;
        #pragma unroll
        for (int it = 0; it < 2; ++it) {
            const int d2 = it * 32 + (t >> 3);
            const int kc = (t & 7) * 8;
            uint4 vv = *(const uint4*)&TB[d2 * 72 + kc];
            *(uint4*)&out[(((size_t)(bb_ * NE + o0 + d2)) << 13)
                          + (rblk & (NS - 1)) + kc] = vv;
        }
    }
}

// ---------------------------------------------------------------------------
// bf16 MFMA flash attention, 3 blocks/CU via 48KB LDS:
// K double-buffered (32KB), V SINGLE-buffered (16KB) — V(r) staged at iter
// top, consumed at GEMM2(r) same iter; its L2/L3-hit latency (~200-400cy,
// qkv output is cache-resident) hides under GEMM1+softmax (~1000cy).
// ks=8 -> grid 1024 -> 3 blocks resident/CU = 3 waves/SIMD (+50% TLP vs
// the 2-wave ceiling that bounded every prior attn round).
// Per-wave structure identical to r2 (proven 116 VGPR <= 170 cap).
// Two barriers/iter: (1) after smax — makes V(r) visible for GEMM2;
// (2) after GEMM2 — protects vbuf before next iter's stage.
// grid 1024, block 256. 8-way merge.
// ---------------------------------------------------------------------------
__global__ __launch_bounds__(256, 3)
void attn_kernel(const unsigned short* __restrict__ qkv,
                 _Float16* __restrict__ pd,      // d_out as fp16 partials (ks 0,1)
                 _Float16* __restrict__ pw,      // ws partials (ks 2..7)
                 float* __restrict__ ml)         // ws [q*8+ks] = l
{
    __shared__ unsigned short kbuf[2][64 * 128];   // 32KB (dbuf)
    __shared__ unsigned short vbuf[64 * 128];      // 16KB (single)

    const int t  = threadIdx.x;
    const int id = blockIdx.x;
    const int ks = id & 7;
    const int b  = (id >> 3) & 1;
    const int T  = id >> 4;

    const unsigned short* Qg = qkv;
    const unsigned short* Kg = qkv + (size_t)NROWS * NE;
    const unsigned short* Vb = qkv + (size_t)2 * NROWS * NE + ((size_t)b << 20);

    const int w = t >> 6, lane = t & 63, lq = lane & 31, h = lane >> 5;
    const int qbw = b * NS + T * 128 + w * 32;
    const size_t kvb = (size_t)b * NS * NE;
    const int kq0 = ks * 1024;

    s8v qf[8];
    #pragma unroll
    for (int s = 0; s < 8; ++s)
        qf[s] = *(const s8v*)(Qg + (size_t)(qbw + lq) * NE + s * 16 + h * 8);

    fx16 acc[4];
    #pragma unroll
    for (int dt = 0; dt < 4; ++dt)
        #pragma unroll
        for (int i = 0; i < 16; ++i) acc[dt][i] = 0.f;

    float l = 0.f;

    // ---- staging pointers: computed once, advanced by constant stride ----
    const unsigned short* gptr[8];
    if (w < 2) {
        #pragma unroll
        for (int j = 0; j < 8; ++j) {
            int i = 8 * w + j;
            int keyl = 4 * i + (lane >> 4);
            int c = (lane & 15) ^ (keyl & 7);
            gptr[j] = Kg + kvb + (size_t)(kq0 + keyl) * NE + c * 8;
        }
    } else {
        #pragma unroll
        for (int j = 0; j < 8; ++j) {
            int i = 8 * (w - 2) + j;
            int d = 8 * i + (lane >> 3);
            int g = (lane & 7) ^ (d & 7);
            gptr[j] = Vb + ((size_t)d << 13) + kq0 + g * 8;
        }
    }
    const int gstride = (w < 2) ? 64 * NE : 64;   // shorts per 64-key tile

    auto stageK = [&](int bufi) {
        if (w < 2) {
            #pragma unroll
            for (int j = 0; j < 8; ++j) {
                __builtin_amdgcn_global_load_lds((as1c*)gptr[j],
                    (as3t*)&kbuf[bufi][(8 * w + j) * 512], 16, 0, 0);
                gptr[j] += gstride;
            }
        }
    };
    auto stageV = [&]() {
        if (w >= 2) {
            #pragma unroll
            for (int j = 0; j < 8; ++j) {
                __builtin_amdgcn_global_load_lds((as1c*)gptr[j],
                    (as3t*)&vbuf[(8 * (w - 2) + j) * 512], 16, 0, 0);
                gptr[j] += gstride;
            }
        }
    };

    const int swz = (lq & 7) * 8;

    // prologue: K(0) -> kbuf0
    stageK(0);
    __syncthreads();

#define PEX(i) (st2[(i) >> 4][(i) & 15])
    int buf = 0;

    for (int r = 0; r < 16; ++r) {
        stageV();                       // V(r) -> vbuf (consumed this iter)
        if (r < 15) stageK(buf ^ 1);    // K(r+1) -> other kbuf

        // ---- GEMM1: S^T[64 key][32 q] = K.Q^T from kbuf[buf] ----
        fx16 st2[2];
        #pragma unroll
        for (int mt = 0; mt < 2; ++mt)
            #pragma unroll
            for (int i = 0; i < 16; ++i) st2[mt][i] = 0.f;
        __builtin_amdgcn_s_setprio(1);
        #pragma unroll
        for (int s = 0; s < 8; ++s) {
            int co = ((s * 2 + h) * 8) ^ swz;
            s8v a0 = *(const s8v*)&kbuf[buf][lq * 128 + co];
            s8v a1 = *(const s8v*)&kbuf[buf][(32 + lq) * 128 + co];
            st2[0] = __builtin_amdgcn_mfma_f32_32x32x16_bf16(a0, qf[s], st2[0], 0, 0, 0);
            st2[1] = __builtin_amdgcn_mfma_f32_32x32x16_bf16(a1, qf[s], st2[1], 0, 0, 0);
        }
        __builtin_amdgcn_s_setprio(0);

        // ---- max-free softmax: P = exp2(score'), tree-sum for l ----
        float a0s = 0.f, a1s = 0.f, a2s = 0.f, a3s = 0.f;
        #pragma unroll
        for (int i = 0; i < 32; i += 4) {
            PEX(i)     = __builtin_amdgcn_exp2f(PEX(i));
            PEX(i + 1) = __builtin_amdgcn_exp2f(PEX(i + 1));
            PEX(i + 2) = __builtin_amdgcn_exp2f(PEX(i + 2));
            PEX(i + 3) = __builtin_amdgcn_exp2f(PEX(i + 3));
            a0s += PEX(i); a1s += PEX(i + 1); a2s += PEX(i + 2); a3s += PEX(i + 3);
        }
        float lsum = (a0s + a1s) + (a2s + a3s);
        lsum += __shfl_xor(lsum, 32);
        l += lsum;

        __syncthreads();   // V(r) staged loads drained & visible to all waves

        // ---- GEMM2: O += P.V from single vbuf ----
        // v_permlane32_swap_b32 vdst, vsrc swaps vdst[32:63] <-> vsrc[0:31]:
        //   elem0 = { lanes0-31: P0,        lanes32-63: P2[lane-32] }
        //   elem1 = { lanes0-31: P0[ln+32], lanes32-63: P2          }
        #pragma unroll
        for (int s2 = 0; s2 < 4; ++s2) {
            unsigned int P0 = cvtpk(PEX(s2 * 8 + 0), PEX(s2 * 8 + 1));
            unsigned int P1 = cvtpk(PEX(s2 * 8 + 2), PEX(s2 * 8 + 3));
            unsigned int P2 = cvtpk(PEX(s2 * 8 + 4), PEX(s2 * 8 + 5));
            unsigned int P3 = cvtpk(PEX(s2 * 8 + 6), PEX(s2 * 8 + 7));
            u2v r02 = __builtin_amdgcn_permlane32_swap(P0, P2, false, false);
            u2v r13 = __builtin_amdgcn_permlane32_swap(P1, P3, false, false);
            union { unsigned int u[4]; s8v v; } pf;
            pf.u[0] = r02.x;
            pf.u[1] = r13.x;
            pf.u[2] = r02.y;
            pf.u[3] = r13.y;
            int go = ((s2 * 2 + h) * 8) ^ swz;
            __builtin_amdgcn_s_setprio(1);
            #pragma unroll
            for (int dt = 0; dt < 4; ++dt) {
                s8v vf = *(const s8v*)&vbuf[(lq + 32 * dt) * 64 + go];
                acc[dt] = __builtin_amdgcn_mfma_f32_32x32x16_bf16(pf.v, vf, acc[dt], 0, 0, 0);
            }
            __builtin_amdgcn_s_setprio(0);
        }

        __syncthreads();   // all vbuf reads done before next iter's stageV
        buf ^= 1;
    }
#undef PEX

    // ---- epilogue: normalize by own l, store fp16 partial + l ----
    if (lane < 32)
        ml[(size_t)(qbw + lq) * 8 + ks] = l;

    float invl = 1.0f / l;
    _Float16* P;
    int rstride, slot;
    if (ks < 2) { P = pd; rstride = 256; slot = ks * 128; }
    else        { P = pw; rstride = 768; slot = (ks - 2) * 128; }
    #pragma unroll
    for (int rg = 0; rg < 16; ++rg) {
        int row = (rg & 3) + 8 * (rg >> 2) + 4 * h;
        float sc = __shfl(invl, row);
        size_t rb = (size_t)(qbw + row) * rstride + slot;
        #pragma unroll
        for (int dt = 0; dt < 4; ++dt)
            P[rb + lq + 32 * dt] = (_Float16)(acc[dt][rg] * sc);
    }
}

// ---------------------------------------------------------------------------
// 8-way l-weighted merge. grid 1024, block 256.
// ---------------------------------------------------------------------------
__global__ __launch_bounds__(256, 2)
void merge_kernel(const _Float16* __restrict__ pw,
                  const float* __restrict__ ml,
                  float* __restrict__ outp)
{
    const int gi = blockIdx.x * 256 + threadIdx.x;
    const int q = gi >> 4, d0 = (gi & 15) * 8;
    const _Float16* pd = (const _Float16*)outp;

    union { uint4 u; _Float16 hh[8]; } c[8];
    c[0].u = *(const uint4*)&pd[(size_t)q * 256 + d0];
    c[1].u = *(const uint4*)&pd[(size_t)q * 256 + 128 + d0];
    #pragma unroll
    for (int p = 0; p < 6; ++p)
        c[2 + p].u = *(const uint4*)&pw[(size_t)q * 768 + p * 128 + d0];

    float4 la = *(const float4*)&ml[q * 8];
    float4 lb = *(const float4*)&ml[q * 8 + 4];
    float inv = 1.f / ((la.x + la.y + la.z + la.w) + (lb.x + lb.y + lb.z + lb.w));
    float wg[8] = { la.x * inv, la.y * inv, la.z * inv, la.w * inv,
                    lb.x * inv, lb.y * inv, lb.z * inv, lb.w * inv };

    float ov[8];
    #pragma unroll
    for (int e = 0; e < 8; ++e) {
        float s = 0.f;
        #pragma unroll
        for (int p = 0; p < 8; ++p)
            s += (float)c[p].hh[e] * wg[p];
        ov[e] = s;
    }

    *(float4*)&outp[(size_t)q * 128 + d0]     = *(float4*)&ov[0];
    *(float4*)&outp[(size_t)q * 128 + d0 + 4] = *(float4*)&ov[4];
}

// ---------------------------------------------------------------------------
extern "C" void kernel_launch(void* const* d_in, const int* in_sizes, int n_in,
                              void* d_out, int out_size, void* d_ws, size_t ws_size,
                              hipStream_t stream)
{
    const float* x  = (const float*)d_in[0];
    const float* Wq = (const float*)d_in[1];
    const float* bq = (const float*)d_in[2];
    const float* Wk = (const float*)d_in[3];
    const float* bk = (const float*)d_in[4];
    const float* Wv = (const float*)d_in[5];
    const float* bv = (const float*)d_in[6];
    float* out = (float*)d_out;

    unsigned char* ws = (unsigned char*)d_ws;
    unsigned short* qkv = (unsigned short*)ws;                       // 12.58 MB
    _Float16* pw = (_Float16*)(ws + (size_t)3 * NROWS * NE * 2);     // 25.17 MB (6 partials)
    float* mlp = (float*)(ws + (size_t)3 * NROWS * NE * 2
                             + (size_t)NROWS * 768 * 2);             // 0.52 MB
    unsigned char* ws2 = ws + (size_t)3 * NROWS * NE * 2
                            + (size_t)NROWS * 768 * 2 + (size_t)NROWS * 32;
    unsigned short* xh  = (unsigned short*)ws2;                      // 4.19 MB
    unsigned short* xl  = xh + (size_t)NROWS * NE;                   // 4.19 MB
    unsigned short* WhS = xl + (size_t)NROWS * NE;                   // 96 KB
    unsigned short* WlS = WhS + 3 * NE * NE;                         // 96 KB

    split_kernel<<<1048, 256, 0, stream>>>(x, Wq, Wk, Wv, xh, xl, WhS, WlS);

    dim3 g1(NROWS / 64, 3, 2);
    qkv_kernel<<<g1, 256, 0, stream>>>(xh, xl, WhS, WlS, bq, bk, bv, qkv);

    attn_kernel<<<1024, 256, 0, stream>>>(qkv, (_Float16*)d_out, pw, mlp);
    merge_kernel<<<1024, 256, 0, stream>>>(pw, mlp, out);
}

// Round 11
// 158.999 us; speedup vs baseline: 1.0759x; 1.0759x over previous
//
#include <hip/hip_runtime.h>
#include <math.h>

#define NB 2
#define NS 8192
#define NE 128
#define NROWS (NB * NS)

typedef __attribute__((ext_vector_type(8))) short s8v;    // 8 bf16 MFMA frag
typedef __attribute__((ext_vector_type(16))) float fx16;  // 32x32 accumulator
typedef __attribute__((ext_vector_type(2))) unsigned int u2v;
typedef __attribute__((address_space(1))) const unsigned char as1c;
typedef __attribute__((address_space(3))) unsigned char as3t;

static __device__ __forceinline__ unsigned int pkbf(float a, float b) {
    unsigned int ua = __float_as_uint(a), ub = __float_as_uint(b);
    ua += 0x7FFFu + ((ua >> 16) & 1u);
    ub += 0x7FFFu + ((ub >> 16) & 1u);
    return (ua >> 16) | (ub & 0xFFFF0000u);
}

// HW packed f32->bf16 (RNE), 1 instr for 2 elements (no builtin on gfx950)
static __device__ __forceinline__ unsigned int cvtpk(float a, float b) {
    unsigned int r;
    asm("v_cvt_pk_bf16_f32 %0, %1, %2" : "=v"(r) : "v"(a), "v"(b));
    return r;
}

// hi/lo split of 8 consecutive floats -> two uint4 of 8 bf16 each
static __device__ __forceinline__ void split8(const float* p, uint4& H, uint4& L) {
    float4 a = *(const float4*)p;
    float4 b = *(const float4*)(p + 4);
    unsigned int h0 = cvtpk(a.x, a.y), h1 = cvtpk(a.z, a.w);
    unsigned int h2 = cvtpk(b.x, b.y), h3 = cvtpk(b.z, b.w);
    H = make_uint4(h0, h1, h2, h3);
    float l0 = a.x - __uint_as_float(h0 << 16);
    float l1 = a.y - __uint_as_float(h0 & 0xFFFF0000u);
    float l2 = a.z - __uint_as_float(h1 << 16);
    float l3 = a.w - __uint_as_float(h1 & 0xFFFF0000u);
    float l4 = b.x - __uint_as_float(h2 << 16);
    float l5 = b.y - __uint_as_float(h2 & 0xFFFF0000u);
    float l6 = b.z - __uint_as_float(h3 << 16);
    float l7 = b.w - __uint_as_float(h3 & 0xFFFF0000u);
    L = make_uint4(cvtpk(l0, l1), cvtpk(l2, l3), cvtpk(l4, l5), cvtpk(l6, l7));
}

// ---------------------------------------------------------------------------
// W-only hi/lo split: 3 x [128][128] f32 -> WhS,WlS bf16 with 8-col-granule
// XOR swizzle (granule g stored at g ^ (row&7)) so qkv can stage LINEARLY
// via global_load_lds and ds_read with the same XOR. grid 24, block 256.
// ---------------------------------------------------------------------------
__global__ __launch_bounds__(256, 4)
void splitW_kernel(const float* __restrict__ Wq, const float* __restrict__ Wk,
                   const float* __restrict__ Wv,
                   unsigned short* __restrict__ WhS, unsigned short* __restrict__ WlS)
{
    const int tid = blockIdx.x * 256 + threadIdx.x;  // 6144 granule tasks
    const int mat = tid >> 11;
    const int rem = tid & 2047;
    const int r = rem >> 4, g = rem & 15;
    const float* W = (mat == 0) ? Wq : (mat == 1) ? Wk : Wv;
    uint4 H, L;
    split8(&W[r * 128 + g * 8], H, L);
    const int gs = g ^ (r & 7);
    *(uint4*)&WhS[mat * 16384 + r * 128 + gs * 8] = H;
    *(uint4*)&WlS[mat * 16384 + r * 128 + gs * 8] = L;
}

// ---------------------------------------------------------------------------
// QKV projection v4: ONE block per 64-row x-tile; loop over all 6 (mat, o0)
// variants so x is read from global exactly ONCE (v1-v3 re-read it 6x —
// the invariant ~30us cost). x loaded f32 coalesced, hi/lo split in-reg,
// ds_written with XOR swizzle. W (pre-split/swizzled, L2-hot) staged per
// variant via global_load_lds single-buffer, overlapped with MFMA.
// LDS 73KB -> 2 blocks/CU. grid 256, block 256 (4 waves = quadrants).
// Q/K: C = W x^T. V: C = x W^T -> Vt[d][key]. Q pre-scaled log2(e)/sqrt(E).
// ---------------------------------------------------------------------------
__global__ __launch_bounds__(256, 2)
void qkv_kernel(const float* __restrict__ x,
                const unsigned short* __restrict__ WhS,
                const unsigned short* __restrict__ WlS,
                const float* __restrict__ bq, const float* __restrict__ bk,
                const float* __restrict__ bv,
                unsigned short* __restrict__ qkv)
{
    __shared__ unsigned short xhL[64 * 128];   // 16KB
    __shared__ unsigned short xlL[64 * 128];   // 16KB
    __shared__ unsigned short WhL[64 * 128];   // 16KB (single buffer)
    __shared__ unsigned short WlL[64 * 128];   // 16KB
    __shared__ unsigned short TB[64 * 72];     // 9KB transpose buffer

    const int t    = threadIdx.x;
    const int rblk = blockIdx.x * 64;
    const int w = t >> 6, lane = t & 63, lq = lane & 31, h = lane >> 5;

    auto stageW = [&](int mo) {
        const int mat = mo >> 1;
        const unsigned short* hs = WhS + mat * 16384 + (mo & 1) * 8192;
        const unsigned short* ls = WlS + mat * 16384 + (mo & 1) * 8192;
        #pragma unroll
        for (int p = 0; p < 4; ++p) {
            __builtin_amdgcn_global_load_lds((as1c*)(hs + p * 2048 + t * 8),
                (as3t*)&WhL[p * 2048 + t * 8], 16, 0, 0);
            __builtin_amdgcn_global_load_lds((as1c*)(ls + p * 2048 + t * 8),
                (as3t*)&WlL[p * 2048 + t * 8], 16, 0, 0);
        }
    };

    // ---- stage x ONCE: coalesced f32 load, in-reg split, swizzled ds_write ----
    {
        const int row = t >> 2, cg0 = (t & 3) * 4;
        #pragma unroll
        for (int g = 0; g < 4; ++g) {
            uint4 H, L;
            split8(&x[(size_t)(rblk + row) * NE + (cg0 + g) * 8], H, L);
            const int gs = (cg0 + g) ^ (row & 7);
            *(uint4*)&xhL[row * 128 + gs * 8] = H;
            *(uint4*)&xlL[row * 128 + gs * 8] = L;
        }
    }
    stageW(0);
    __syncthreads();   // x in LDS, W(0) staged (barrier drains global_load_lds)

    // ---- per-wave quadrant: rows rloc..+31, out cols ot*32..+31 (of o0) ----
    const int rloc = (w & 1) * 32;
    const int ot   = w >> 1;

    // hoisted x fragments (read once, reused by all 6 variants)
    s8v xhf[8], xlf[8];
    #pragma unroll
    for (int s = 0; s < 8; ++s) {
        const int cx = ((s * 2 + h) ^ (lq & 7)) * 8;
        xhf[s] = *(const s8v*)&xhL[(rloc + lq) * 128 + cx];
        xlf[s] = *(const s8v*)&xlL[(rloc + lq) * 128 + cx];
    }

    for (int mo = 0; mo < 6; ++mo) {
        const int mat = mo >> 1, o0 = (mo & 1) * 64;
        const float* bias = (mat == 0) ? bq : (mat == 1) ? bk : bv;
        unsigned short* out = qkv + (size_t)mat * NROWS * NE;
        const float osc = (mat == 0) ? 0.1275174460620886f : 1.0f; // log2e/sqrt(128)

        // W(mo) fragments (guaranteed staged by previous bottom barrier)
        s8v whf[8], wlf[8];
        #pragma unroll
        for (int s = 0; s < 8; ++s) {
            const int cx = ((s * 2 + h) ^ (lq & 7)) * 8;
            whf[s] = *(const s8v*)&WhL[(ot * 32 + lq) * 128 + cx];
            wlf[s] = *(const s8v*)&WlL[(ot * 32 + lq) * 128 + cx];
        }
        __syncthreads();              // all W reads done -> safe to overwrite
        if (mo < 5) stageW(mo + 1);   // overlaps MFMA + epilogue below

        fx16 acc;
        #pragma unroll
        for (int i = 0; i < 16; ++i) acc[i] = 0.f;

        #pragma unroll
        for (int s = 0; s < 8; ++s) {
            if (mat != 2) {
                acc = __builtin_amdgcn_mfma_f32_32x32x16_bf16(whf[s], xhf[s], acc, 0, 0, 0);
                acc = __builtin_amdgcn_mfma_f32_32x32x16_bf16(whf[s], xlf[s], acc, 0, 0, 0);
                acc = __builtin_amdgcn_mfma_f32_32x32x16_bf16(wlf[s], xhf[s], acc, 0, 0, 0);
            } else {
                acc = __builtin_amdgcn_mfma_f32_32x32x16_bf16(xhf[s], whf[s], acc, 0, 0, 0);
                acc = __builtin_amdgcn_mfma_f32_32x32x16_bf16(xlf[s], whf[s], acc, 0, 0, 0);
                acc = __builtin_amdgcn_mfma_f32_32x32x16_bf16(xhf[s], wlf[s], acc, 0, 0, 0);
            }
        }

        // ---- transpose epilogue through TB -> coalesced 16B stores ----
        if (mat != 2) {
            #pragma unroll
            for (int g = 0; g < 4; ++g) {
                const int ob = o0 + ot * 32 + 4 * h + 8 * g;
                float4 bb = *(const float4*)&bias[ob];
                float v0 = (acc[4 * g + 0] + bb.x) * osc;
                float v1 = (acc[4 * g + 1] + bb.y) * osc;
                float v2 = (acc[4 * g + 2] + bb.z) * osc;
                float v3 = (acc[4 * g + 3] + bb.w) * osc;
                *(uint2*)&TB[(rloc + lq) * 72 + ot * 32 + 4 * h + 8 * g] =
                    make_uint2(pkbf(v0, v1), pkbf(v2, v3));
            }
            __syncthreads();   // TB visible; W(mo+1) loads drained
            #pragma unroll
            for (int it = 0; it < 2; ++it) {
                const int r2 = it * 32 + (t >> 3);
                const int c2 = (t & 7) * 8;
                uint4 vv = *(const uint4*)&TB[r2 * 72 + c2];
                *(uint4*)&out[(size_t)(rblk + r2) * NE + o0 + c2] = vv;
            }
        } else {
            const float bv_ = bias[o0 + ot * 32 + lq];
            #pragma unroll
            for (int g = 0; g < 4; ++g) {
                float v0 = acc[4 * g + 0] + bv_;
                float v1 = acc[4 * g + 1] + bv_;
                float v2 = acc[4 * g + 2] + bv_;
                float v3 = acc[4 * g + 3] + bv_;
                *(uint2*)&TB[(ot * 32 + lq) * 72 + rloc + 4 * h + 8 * g] =
                    make_uint2(pkbf(v0, v1), pkbf(v2, v3));
            }
            __syncthreads();   // TB visible; W(mo+1) loads drained
            const int bb_ = rblk >> 13;
            #pragma unroll
            for (int it = 0; it < 2; ++it) {
                const int d2 = it * 32 + (t >> 3);
                const int kc = (t & 7) * 8;
                uint4 vv = *(const uint4*)&TB[d2 * 72 + kc];
                *(uint4*)&out[(((size_t)(bb_ * NE + o0 + d2)) << 13)
                              + (rblk & (NS - 1)) + kc] = vv;
            }
        }
        // next loop-top W-frag read: W(mo+1) guaranteed by the barrier above;
        // next TB overwrite guarded by next iteration's post-read barrier.
    }
}

// ---------------------------------------------------------------------------
// bf16 MFMA flash attention, SOFTWARE-PIPELINED one tile ahead (r9 verbatim,
// best verified: 82.7 us — structurally LDS-BW-bound at this geometry).
// grid 512, block 256, 2 blocks/CU.
// ---------------------------------------------------------------------------
__global__ __launch_bounds__(256, 2)
void attn_kernel(const unsigned short* __restrict__ qkv,
                 _Float16* __restrict__ pd,      // d_out as fp16 partials
                 _Float16* __restrict__ pw,      // ws partials
                 float* __restrict__ ml)         // ws [q*4+ks] = l
{
    __shared__ unsigned short kbuf[2][64 * 128];
    __shared__ unsigned short vbuf[2][64 * 128];

    const int t  = threadIdx.x;
    const int id = blockIdx.x;
    const int ks = id & 3;
    const int b  = (id >> 2) & 1;
    const int T  = id >> 3;

    const unsigned short* Qg = qkv;
    const unsigned short* Kg = qkv + (size_t)NROWS * NE;
    const unsigned short* Vb = qkv + (size_t)2 * NROWS * NE + ((size_t)b << 20);

    const int w = t >> 6, lane = t & 63, lq = lane & 31, h = lane >> 5;
    const int qbw = b * NS + T * 128 + w * 32;
    const size_t kvb = (size_t)b * NS * NE;
    const int kq0 = ks * 2048;

    s8v qf[8];
    #pragma unroll
    for (int s = 0; s < 8; ++s)
        qf[s] = *(const s8v*)(Qg + (size_t)(qbw + lq) * NE + s * 16 + h * 8);

    fx16 acc[4];
    #pragma unroll
    for (int dt = 0; dt < 4; ++dt)
        #pragma unroll
        for (int i = 0; i < 16; ++i) acc[dt][i] = 0.f;

    float l = 0.f;

    // ---- staging pointers: computed once, advanced by constant stride ----
    const unsigned short* gptr[8];
    if (w < 2) {
        #pragma unroll
        for (int j = 0; j < 8; ++j) {
            int i = 8 * w + j;
            int keyl = 4 * i + (lane >> 4);
            int c = (lane & 15) ^ (keyl & 7);
            gptr[j] = Kg + kvb + (size_t)(kq0 + keyl) * NE + c * 8;
        }
    } else {
        #pragma unroll
        for (int j = 0; j < 8; ++j) {
            int i = 8 * (w - 2) + j;
            int d = 8 * i + (lane >> 3);
            int g = (lane & 7) ^ (d & 7);
            gptr[j] = Vb + ((size_t)d << 13) + kq0 + g * 8;
        }
    }
    const int gstride = (w < 2) ? 64 * NE : 64;   // shorts per 64-key tile

    auto stageK = [&](int bufi) {
        if (w < 2) {
            #pragma unroll
            for (int j = 0; j < 8; ++j) {
                __builtin_amdgcn_global_load_lds((as1c*)gptr[j],
                    (as3t*)&kbuf[bufi][(8 * w + j) * 512], 16, 0, 0);
                gptr[j] += gstride;
            }
        }
    };
    auto stageV = [&](int bufi) {
        if (w >= 2) {
            #pragma unroll
            for (int j = 0; j < 8; ++j) {
                __builtin_amdgcn_global_load_lds((as1c*)gptr[j],
                    (as3t*)&vbuf[bufi][(8 * (w - 2) + j) * 512], 16, 0, 0);
                gptr[j] += gstride;
            }
        }
    };

    const int swz = (lq & 7) * 8;

    auto gemm1 = [&](fx16 (&st)[2], int bufi) {
        #pragma unroll
        for (int mt = 0; mt < 2; ++mt)
            #pragma unroll
            for (int i = 0; i < 16; ++i) st[mt][i] = 0.f;
        __builtin_amdgcn_s_setprio(1);
        #pragma unroll
        for (int s = 0; s < 8; ++s) {
            int co = ((s * 2 + h) * 8) ^ swz;
            s8v a0 = *(const s8v*)&kbuf[bufi][lq * 128 + co];
            s8v a1 = *(const s8v*)&kbuf[bufi][(32 + lq) * 128 + co];
            st[0] = __builtin_amdgcn_mfma_f32_32x32x16_bf16(a0, qf[s], st[0], 0, 0, 0);
            st[1] = __builtin_amdgcn_mfma_f32_32x32x16_bf16(a1, qf[s], st[1], 0, 0, 0);
        }
        __builtin_amdgcn_s_setprio(0);
    };

#define PEX(st, i) (st[(i) >> 4][(i) & 15])
    auto smax = [&](fx16 (&st)[2]) {
        float a0s = 0.f, a1s = 0.f, a2s = 0.f, a3s = 0.f;
        #pragma unroll
        for (int i = 0; i < 32; i += 4) {
            PEX(st, i)     = __builtin_amdgcn_exp2f(PEX(st, i));
            PEX(st, i + 1) = __builtin_amdgcn_exp2f(PEX(st, i + 1));
            PEX(st, i + 2) = __builtin_amdgcn_exp2f(PEX(st, i + 2));
            PEX(st, i + 3) = __builtin_amdgcn_exp2f(PEX(st, i + 3));
            a0s += PEX(st, i); a1s += PEX(st, i + 1);
            a2s += PEX(st, i + 2); a3s += PEX(st, i + 3);
        }
        float lsum = (a0s + a1s) + (a2s + a3s);
        lsum += __shfl_xor(lsum, 32);
        l += lsum;
    };

    auto gemm2 = [&](fx16 (&st)[2], int bufi) {
        // v_permlane32_swap_b32 vdst, vsrc swaps vdst[32:63] <-> vsrc[0:31]:
        //   elem0 = { lanes0-31: P0,        lanes32-63: P2[lane-32] }
        //   elem1 = { lanes0-31: P0[ln+32], lanes32-63: P2          }
        #pragma unroll
        for (int s2 = 0; s2 < 4; ++s2) {
            unsigned int P0 = cvtpk(PEX(st, s2 * 8 + 0), PEX(st, s2 * 8 + 1));
            unsigned int P1 = cvtpk(PEX(st, s2 * 8 + 2), PEX(st, s2 * 8 + 3));
            unsigned int P2 = cvtpk(PEX(st, s2 * 8 + 4), PEX(st, s2 * 8 + 5));
            unsigned int P3 = cvtpk(PEX(st, s2 * 8 + 6), PEX(st, s2 * 8 + 7));
            u2v r02 = __builtin_amdgcn_permlane32_swap(P0, P2, false, false);
            u2v r13 = __builtin_amdgcn_permlane32_swap(P1, P3, false, false);
            union { unsigned int u[4]; s8v v; } pf;
            pf.u[0] = r02.x;
            pf.u[1] = r13.x;
            pf.u[2] = r02.y;
            pf.u[3] = r13.y;
            int go = ((s2 * 2 + h) * 8) ^ swz;
            __builtin_amdgcn_s_setprio(1);
            #pragma unroll
            for (int dt = 0; dt < 4; ++dt) {
                s8v vf = *(const s8v*)&vbuf[bufi][(lq + 32 * dt) * 64 + go];
                acc[dt] = __builtin_amdgcn_mfma_f32_32x32x16_bf16(pf.v, vf, acc[dt], 0, 0, 0);
            }
            __builtin_amdgcn_s_setprio(0);
        }
    };

    // ---- prologue: tile0 in buf0; S(0) computed; K(1) staged ----
    stageK(0);                 // K(0) -> kbuf0
    stageV(0);                 // V(0) -> vbuf0
    __syncthreads();
    fx16 stA[2], stB[2];
    gemm1(stA, 0);             // S(0)
    stageK(1);                 // K(1) -> kbuf1
    __syncthreads();

    // ---- pipelined main loop: 2 tiles per pass (even=bufs 0, odd=bufs 1) ----
    for (int r2 = 0; r2 < 16; ++r2) {
        const bool notlast = (r2 < 15);
        // even tile t = 2*r2: S in stA
        if (notlast) stageK(0);    // K(t+2) -> kbuf0
        stageV(1);                 // V(t+1) -> vbuf1
        smax(stA);
        gemm1(stB, 1);             // S(t+1) from K(t+1)
        gemm2(stA, 0);             // O += P(t) . V(t)
        __syncthreads();
        // odd tile t+1: S in stB
        if (notlast) {
            stageK(1);             // K(t+3) -> kbuf1
            stageV(0);             // V(t+2) -> vbuf0
        }
        smax(stB);
        if (notlast) gemm1(stA, 0);  // S(t+2) from K(t+2)
        gemm2(stB, 1);             // O += P(t+1) . V(t+1)
        __syncthreads();
    }
#undef PEX

    // ---- epilogue: normalize by own l, store fp16 partial + l ----
    if (lane < 32)
        ml[(size_t)(qbw + lq) * 4 + ks] = l;

    float invl = 1.0f / l;
    _Float16* P = (ks < 2) ? pd : pw;
    const int slot = (ks & 1) * 128;
    #pragma unroll
    for (int rg = 0; rg < 16; ++rg) {
        int row = (rg & 3) + 8 * (rg >> 2) + 4 * h;
        float sc = __shfl(invl, row);
        size_t rb = (size_t)(qbw + row) * 256 + slot;
        #pragma unroll
        for (int dt = 0; dt < 4; ++dt)
            P[rb + lq + 32 * dt] = (_Float16)(acc[dt][rg] * sc);
    }
}

// ---------------------------------------------------------------------------
// 4-way l-weighted merge. grid 1024, block 256.
// ---------------------------------------------------------------------------
__global__ __launch_bounds__(256, 2)
void merge_kernel(const _Float16* __restrict__ pw,
                  const float* __restrict__ ml,
                  float* __restrict__ outp)
{
    const int gi = blockIdx.x * 256 + threadIdx.x;
    const int q = gi >> 4, d0 = (gi & 15) * 8;
    const _Float16* pd = (const _Float16*)outp;

    uint4 u0 = *(const uint4*)&pd[(size_t)q * 256 + d0];
    uint4 u1 = *(const uint4*)&pd[(size_t)q * 256 + 128 + d0];
    uint4 u2 = *(const uint4*)&pw[(size_t)q * 256 + d0];
    uint4 u3 = *(const uint4*)&pw[(size_t)q * 256 + 128 + d0];
    float l0 = ml[q * 4 + 0], l1 = ml[q * 4 + 1];
    float l2 = ml[q * 4 + 2], l3 = ml[q * 4 + 3];

    float inv = 1.f / (l0 + l1 + l2 + l3);
    float a0 = l0 * inv, a1 = l1 * inv, a2 = l2 * inv, a3 = l3 * inv;

    union { uint4 u; _Float16 hh[8]; } c0, c1, c2, c3;
    c0.u = u0; c1.u = u1; c2.u = u2; c3.u = u3;
    float ov[8];
    #pragma unroll
    for (int e = 0; e < 8; ++e)
        ov[e] = (float)c0.hh[e] * a0 + (float)c1.hh[e] * a1 +
                (float)c2.hh[e] * a2 + (float)c3.hh[e] * a3;

    *(float4*)&outp[(size_t)q * 128 + d0]     = *(float4*)&ov[0];
    *(float4*)&outp[(size_t)q * 128 + d0 + 4] = *(float4*)&ov[4];
}

// ---------------------------------------------------------------------------
extern "C" void kernel_launch(void* const* d_in, const int* in_sizes, int n_in,
                              void* d_out, int out_size, void* d_ws, size_t ws_size,
                              hipStream_t stream)
{
    const float* x  = (const float*)d_in[0];
    const float* Wq = (const float*)d_in[1];
    const float* bq = (const float*)d_in[2];
    const float* Wk = (const float*)d_in[3];
    const float* bk = (const float*)d_in[4];
    const float* Wv = (const float*)d_in[5];
    const float* bv = (const float*)d_in[6];
    float* out = (float*)d_out;

    unsigned char* ws = (unsigned char*)d_ws;
    unsigned short* qkv = (unsigned short*)ws;                       // 12.58 MB
    _Float16* pw = (_Float16*)(ws + (size_t)3 * NROWS * NE * 2);     // 8.39 MB
    float* mlp = (float*)(ws + (size_t)3 * NROWS * NE * 2
                             + (size_t)NROWS * 256 * 2);             // 0.26 MB
    unsigned short* WhS = (unsigned short*)(ws + (size_t)3 * NROWS * NE * 2
                             + (size_t)NROWS * 256 * 2 + (size_t)NROWS * 16);  // 96 KB
    unsigned short* WlS = WhS + 3 * NE * NE;                         // 96 KB

    splitW_kernel<<<24, 256, 0, stream>>>(Wq, Wk, Wv, WhS, WlS);

    qkv_kernel<<<NROWS / 64, 256, 0, stream>>>(x, WhS, WlS, bq, bk, bv, qkv);

    attn_kernel<<<512, 256, 0, stream>>>(qkv, (_Float16*)d_out, pw, mlp);
    merge_kernel<<<1024, 256, 0, stream>>>(pw, mlp, out);
}